// Round 1
// baseline (432.150 us; speedup 1.0000x reference)
//
#include <hip/hip_runtime.h>

#define B_  32
#define IN_ 4096
#define N_  2048
#define P_  128
#define M_  256
#define D_  10

typedef _Float16 f16;
typedef f16  f16x4   __attribute__((ext_vector_type(4)));
typedef f16  f16x8   __attribute__((ext_vector_type(8)));
typedef float f32x4  __attribute__((ext_vector_type(4)));
typedef float floatx4 __attribute__((ext_vector_type(4)));

union F8 { f16x8 v; f16x4 h[2]; };

__device__ __forceinline__ float sigmoidf_(float z) {
    return __builtin_amdgcn_rcpf(1.0f + __expf(-z));
}

// One block = one neuron n. 256 threads = 4 waves.
// Wave w owns output columns m in {64*ck + 16*w + [0,16)} for ck=0..3.
// MFMA 16x16x32 f16: A=bits (rows=b), B=keys^T (cols=m), C: col=lane&15, row=(lane>>4)*4+reg.
// K-fragment map phi(lhi,e) = 16*(e>>2) + 4*lhi + (e&3), applied identically to A and B
// (dot invariant under any common K permutation).
// LDS rows swizzled on 8B units: element (row,p) at [row][ ((p>>2) ^ (row&15))*4 + (p&3) ].
__global__ __launch_bounds__(256, 3) void vgram_kernel(
    const float* __restrict__ x, const int* __restrict__ idx_a, const int* __restrict__ idx_b,
    const float* __restrict__ keys_raw, const float* __restrict__ values, float* __restrict__ out)
{
    const int n   = blockIdx.x;
    const int t   = threadIdx.x;
    const int l   = t & 63;
    const int wv  = t >> 6;
    const int lhi = l >> 4;
    const int l15 = l & 15;

    __shared__ __align__(16) int s_ia[P_], s_ib[P_];
    __shared__ __align__(16) f16 s_bits[B_][P_];   // swizzled
    __shared__ __align__(16) f16 s_keys[64][P_];   // one 64-m chunk, swizzled
    __shared__ __align__(16) f16 s_w[B_][M_];      // swizzled
    __shared__ __align__(16) f16 s_val[M_][18];    // row-major, padded stride
    __shared__ float s_bsq[B_];
    __shared__ float s_ksq[M_];

    // ---- phase 0: indices + values staging ----
    if (t < 128) { s_ia[t] = idx_a[n * P_ + t]; }
    else         { int tt = t - 128; s_ib[tt] = idx_b[n * P_ + tt]; }
    {
        const float* vb = values + (size_t)n * (M_ * D_);
        #pragma unroll
        for (int it = 0; it < 10; ++it) {
            int f = it * 256 + t;          // 0..2559, coalesced
            float vvv = vb[f];
            int m = f / 10, d = f % 10;
            s_val[m][d] = (f16)vvv;
        }
        s_val[t][10] = (f16)1.0f;          // ones column -> softmax denominator
        #pragma unroll
        for (int dd = 11; dd < 16; ++dd) s_val[t][dd] = (f16)0.0f;
    }
    __syncthreads();

    // ---- phase 1: bits = sigmoid(x[b,ia]-x[b,ib]), b_sq ----
    #pragma unroll
    for (int it = 0; it < 4; ++it) {
        int sig = it * 256 + t;            // 1024 quads: b = sig>>5, q = sig&31
        int b = sig >> 5, q = sig & 31;
        const float* xr = x + b * IN_;
        float partial = 0.f;
        f16x4 hh;
        #pragma unroll
        for (int r = 0; r < 4; ++r) {
            int p = q * 4 + r;
            float z = xr[s_ia[p]] - xr[s_ib[p]];
            float s = sigmoidf_(z);
            f16 hs = (f16)s;
            float hf = (float)hs;
            partial += hf * hf;            // b_sq from ROUNDED bits (consistent metric)
            hh[r] = hs;
        }
        *(f16x4*)&s_bits[b][((q ^ (b & 15)) << 2)] = hh;
        #pragma unroll
        for (int off = 1; off < 32; off <<= 1)
            partial += __shfl_xor(partial, off, 32);
        if ((t & 31) == 0) s_bsq[b] = partial;   // each b exactly once
    }
    __syncthreads();

    // ---- A-fragment preload (bits), resident across all chunks ----
    F8 afrag[2][4];
    #pragma unroll
    for (int rt = 0; rt < 2; ++rt) {
        int b = rt * 16 + l15;
        #pragma unroll
        for (int ks = 0; ks < 4; ++ks) {
            int u1 = (ks * 8 + lhi) ^ l15;   // swizzle key b&15 == l15
            int u2 = u1 ^ 4;
            afrag[rt][ks].h[0] = *(const f16x4*)&s_bits[b][u1 << 2];
            afrag[rt][ks].h[1] = *(const f16x4*)&s_bits[b][u2 << 2];
        }
    }

    f32x4 acc[4][2] = {};   // [chunk][row-tile]

    const float* kb_base = keys_raw + (size_t)n * (M_ * P_);
    #pragma unroll
    for (int ck = 0; ck < 4; ++ck) {
        // ---- stage 64-m key chunk: sigmoid + f16 + k_sq ----
        const float* kb = kb_base + ck * (64 * P_);
        #pragma unroll
        for (int it = 0; it < 8; ++it) {
            int f = it * 256 + t;           // coalesced float4
            int m = f >> 5, q = f & 31;
            floatx4 kvv = *(const floatx4*)(kb + f * 4);
            float partial = 0.f;
            f16x4 hh;
            #pragma unroll
            for (int r = 0; r < 4; ++r) {
                float s = sigmoidf_(kvv[r]);
                f16 hs = (f16)s;
                float hf = (float)hs;
                partial += hf * hf;
                hh[r] = hs;
            }
            *(f16x4*)&s_keys[m][((q ^ (m & 15)) << 2)] = hh;
            #pragma unroll
            for (int off = 1; off < 32; off <<= 1)
                partial += __shfl_xor(partial, off, 32);
            if ((t & 31) == 0) s_ksq[ck * 64 + m] = partial;
        }
        __syncthreads();

        // ---- dots MFMA: wave wv consumes rows 16*wv..16*wv+15 of the chunk ----
        int mrow = wv * 16 + l15;           // mrow&15 == l15
        #pragma unroll
        for (int ks = 0; ks < 4; ++ks) {
            int u1 = (ks * 8 + lhi) ^ l15;
            int u2 = u1 ^ 4;
            F8 bfrag;
            bfrag.h[0] = *(const f16x4*)&s_keys[mrow][u1 << 2];
            bfrag.h[1] = *(const f16x4*)&s_keys[mrow][u2 << 2];
            acc[ck][0] = __builtin_amdgcn_mfma_f32_16x16x32_f16(afrag[0][ks].v, bfrag.v, acc[ck][0], 0, 0, 0);
            acc[ck][1] = __builtin_amdgcn_mfma_f32_16x16x32_f16(afrag[1][ks].v, bfrag.v, acc[ck][1], 0, 0, 0);
        }
        __syncthreads();   // protect s_keys overwrite
    }

    // ---- epilogue 1: dist -> w = exp(-dist) into s_w (f16, swizzled) ----
    #pragma unroll
    for (int ck = 0; ck < 4; ++ck) {
        int mg = ck * 64 + wv * 16 + l15;
        float ksq = s_ksq[mg];
        #pragma unroll
        for (int rt = 0; rt < 2; ++rt) {
            #pragma unroll
            for (int reg = 0; reg < 4; ++reg) {
                int b = rt * 16 + lhi * 4 + reg;      // C row map (verified)
                float dots = acc[ck][rt][reg];
                float d2 = s_bsq[b] + ksq - 2.f * dots;
                d2 = fmaxf(d2, 0.f) + 1e-12f;
                float dist = sqrtf(d2);
                float wexp = __expf(-dist);           // dist>=0 -> in (0,1], no max needed
                int u = mg >> 2;
                s_w[b][((u ^ (b & 15)) << 2) | (mg & 3)] = (f16)wexp;
            }
        }
    }
    __syncthreads();

    // ---- epilogue 2 (wave 0): out = (w @ [values|1]) / sum ----
    if (wv == 0) {
        f32x4 c2[2] = {};
        #pragma unroll
        for (int ks2 = 0; ks2 < 8; ++ks2) {
            F8 bfrag;                                  // B: values, col d = l15, k = m
            #pragma unroll
            for (int e = 0; e < 8; ++e) {
                int mm = ks2 * 32 + (e >> 2) * 16 + lhi * 4 + (e & 3);
                bfrag.h[e >> 2][e & 3] = s_val[mm][l15];
            }
            #pragma unroll
            for (int rt = 0; rt < 2; ++rt) {
                int b = rt * 16 + l15;                 // A row b == l15 (+16rt): swz key == l15
                int u1 = (ks2 * 8 + lhi) ^ l15;
                int u2 = u1 ^ 4;
                F8 af;
                af.h[0] = *(const f16x4*)&s_w[b][u1 << 2];
                af.h[1] = *(const f16x4*)&s_w[b][u2 << 2];
                c2[rt] = __builtin_amdgcn_mfma_f32_16x16x32_f16(af.v, bfrag.v, c2[rt], 0, 0, 0);
            }
        }
        #pragma unroll
        for (int rt = 0; rt < 2; ++rt) {
            #pragma unroll
            for (int reg = 0; reg < 4; ++reg) {
                float sum = __shfl(c2[rt][reg], (l & 48) | 10, 64);  // ones-column
                float rs = 1.0f / sum;
                if (l15 < 10) {
                    int b = rt * 16 + lhi * 4 + reg;
                    out[((size_t)b * N_ + n) * D_ + l15] = c2[rt][reg] * rs;
                }
            }
        }
    }
}

extern "C" void kernel_launch(void* const* d_in, const int* in_sizes, int n_in,
                              void* d_out, int out_size, void* d_ws, size_t ws_size,
                              hipStream_t stream) {
    const float* x    = (const float*)d_in[0];
    const int*   ia   = (const int*)d_in[1];
    const int*   ib   = (const int*)d_in[2];
    const float* keys = (const float*)d_in[3];
    const float* vals = (const float*)d_in[4];
    float* o = (float*)d_out;
    vgram_kernel<<<dim3(N_), dim3(256), 0, stream>>>(x, ia, ib, keys, vals, o);
}